// Round 18
// baseline (289.819 us; speedup 1.0000x reference)
//
#include <hip/hip_runtime.h>

#define NN   100000
#define NE   1600000
#define IND  256
#define HIDD 128
#define BCAP 64      // per-node bucket capacity (max in-degree ~40 for this input)
#define FTAIL 602112 // edges [0,FTAIL) filled inside gemm launches; rest standalone

typedef __attribute__((ext_vector_type(8))) short short8v;
typedef __attribute__((ext_vector_type(4))) float f32x4;

// ---------------- bf16 helpers ----------------------------------------------
__device__ inline float bflo(unsigned w) { return __uint_as_float(w << 16); }
__device__ inline float bfhi(unsigned w) { return __uint_as_float(w & 0xffff0000u); }
__device__ inline unsigned packbf2(float x, float y) {   // RNE round both
  unsigned xb = __float_as_uint(x);
  unsigned yb = __float_as_uint(y);
  xb += 0x7fffu + ((xb >> 16) & 1u);
  yb += 0x7fffu + ((yb >> 16) & 1u);
  return (xb >> 16) | (yb & 0xffff0000u);
}
__device__ inline unsigned short bf16r(float x) {        // RNE round one
  unsigned b = __float_as_uint(x);
  b += 0x7fffu + ((b >> 16) & 1u);
  return (unsigned short)(b >> 16);
}

// ---------------- fused: MFMA GEMM tile | right-sized fill slices -------------
// GEMM tile: C = relu(A @ B^T + bias), 128x128, 4 waves, BK=32 (LDS 20.5KB).
// Fill rate is CONTEXT-DEPENDENT (r16/r17 data): ~5.6 G/s beside K=256 gemm,
// ~8.5 beside K=128, 12.6 standalone. r16 oversized slices -> launches ran at
// fill-time (71us) not gemm-time (~35/20). Fix: each launch carries only what
// its gemm time hides (200K edges, 98 ILP-8 blocks); the rest fills standalone
// at full rate. Pattern: bid%9==8 -> fill block (2048 edges, 8 indep chains);
// else gemm gb=(bid/9)*8+r.
// NOTE (r15): grid.sync() ~140us/barrier on 8-XCD MI355X — never again.
#define APITCH 40   // padded row pitch in bf16 elems (32 + 8): 80 B, 16B-aligned
template<int A_FP32>
__global__ __launch_bounds__(256) void fused_gemm_fill(
    const void* __restrict__ Aptr, const float* __restrict__ Bf,
    const float* __restrict__ bias, unsigned short* __restrict__ Cb,
    int M, int K, int ng,
    const int* __restrict__ src, const int* __restrict__ dst,
    int estart, int eend, int* __restrict__ cursor, int* __restrict__ colbuk)
{
  __shared__ unsigned short lA[128 * APITCH];
  __shared__ unsigned short lB[128 * APITCH];
  const int tid = threadIdx.x;
  const int bid = blockIdx.x;
  const int r = bid % 9;

  if (r == 8) {                           // ---- fill block: 2048 edges, ILP-8
    int base = estart + (bid / 9) * 2048;
    int fd[8], fs[8], fp[8];
#pragma unroll
    for (int i = 0; i < 8; ++i) {
      int e = base + i * 256 + tid;
      bool v = e < eend;
      fd[i] = v ? dst[e] : -1;
      fs[i] = v ? src[e] : 0;
    }
#pragma unroll
    for (int i = 0; i < 8; ++i)
      fp[i] = (fd[i] >= 0) ? atomicAdd(&cursor[fd[i]], 1) : BCAP;
#pragma unroll
    for (int i = 0; i < 8; ++i)
      if (fp[i] < BCAP) colbuk[(size_t)fd[i] * BCAP + fp[i]] = fs[i];
    return;
  }
  int gb = (bid / 9) * 8 + r;
  if (gb >= ng) return;

  const int lane = tid & 63, wid = tid >> 6;
  const int wr = wid >> 1, wc = wid & 1;
  const int bm = gb * 128;
  const int lr = lane & 15, lg = lane >> 4;

  f32x4 acc[4][4];
#pragma unroll
  for (int i = 0; i < 4; ++i)
#pragma unroll
    for (int j = 0; j < 4; ++j) acc[i][j] = (f32x4){0.f, 0.f, 0.f, 0.f};

  for (int k0 = 0; k0 < K; k0 += 32) {
    // stage A-tile [128][32] and B-tile [128][32]; 512 slots of 8 bf16
#pragma unroll
    for (int s0 = 0; s0 < 512; s0 += 256) {
      int s = s0 + tid;
      int rr = s >> 2, g = s & 3;
      int grow = bm + rr;
      if (A_FP32) {
        float4 v0 = make_float4(0.f, 0.f, 0.f, 0.f);
        float4 v1 = v0;
        if (grow < M) {
          const float* ap = (const float*)Aptr + (size_t)grow * K + k0 + g * 8;
          v0 = ((const float4*)ap)[0];
          v1 = ((const float4*)ap)[1];
        }
        uint4 pk;
        pk.x = packbf2(v0.x, v0.y); pk.y = packbf2(v0.z, v0.w);
        pk.z = packbf2(v1.x, v1.y); pk.w = packbf2(v1.z, v1.w);
        *(uint4*)&lA[rr * APITCH + g * 8] = pk;
      } else {
        uint4 v = make_uint4(0u, 0u, 0u, 0u);
        if (grow < M)
          v = *(const uint4*)((const unsigned short*)Aptr + (size_t)grow * K + k0 + g * 8);
        *(uint4*)&lA[rr * APITCH + g * 8] = v;
      }
      {  // B: fp32 weights -> bf16 in staging
        const float* bp = Bf + (size_t)rr * K + k0 + g * 8;
        float4 w0 = ((const float4*)bp)[0];
        float4 w1 = ((const float4*)bp)[1];
        uint4 pk;
        pk.x = packbf2(w0.x, w0.y); pk.y = packbf2(w0.z, w0.w);
        pk.z = packbf2(w1.x, w1.y); pk.w = packbf2(w1.z, w1.w);
        *(uint4*)&lB[rr * APITCH + g * 8] = pk;
      }
    }
    __syncthreads();
    {
      short8v a[4], b[4];
#pragma unroll
      for (int i = 0; i < 4; ++i)
        a[i] = *(const short8v*)&lA[(wr * 64 + i * 16 + lr) * APITCH + lg * 8];
#pragma unroll
      for (int j = 0; j < 4; ++j)
        b[j] = *(const short8v*)&lB[(wc * 64 + j * 16 + lr) * APITCH + lg * 8];
#pragma unroll
      for (int i = 0; i < 4; ++i)
#pragma unroll
        for (int j = 0; j < 4; ++j)
          acc[i][j] = __builtin_amdgcn_mfma_f32_16x16x32_bf16(a[i], b[j], acc[i][j], 0, 0, 0);
    }
    __syncthreads();
  }

  // epilogue: C/D layout col=lane&15, row=(lane>>4)*4+e  (m89-verified)
#pragma unroll
  for (int i = 0; i < 4; ++i)
#pragma unroll
    for (int e = 0; e < 4; ++e) {
      int row = bm + wr * 64 + i * 16 + lg * 4 + e;
      if (row < M) {
#pragma unroll
        for (int j = 0; j < 4; ++j) {
          int cc = wc * 64 + j * 16 + lr;
          float t = fmaxf(acc[i][j][e] + bias[cc], 0.f);
          Cb[(size_t)row * 128 + cc] = bf16r(t);
        }
      }
    }
}

// ---------------- standalone fill tail: full-rate (no LDS cap) ----------------
// ILP-2 x full TLP: 1950 blocks x 256 thr (near-full residency, no LDS) with
// 2 independent atomic->scatter chains/thread — the 12.6 Gedge/s regime (r6).
__global__ __launch_bounds__(256, 8) void bucket_fill_tail(
    const int* __restrict__ src, const int* __restrict__ dst,
    int* __restrict__ cursor, int* __restrict__ colbuk)
{
  int base = FTAIL + blockIdx.x * 512 + threadIdx.x;
  int fd[2], fs[2], fp[2];
#pragma unroll
  for (int i = 0; i < 2; ++i) {
    int e = base + i * 256;
    bool v = e < NE;
    fd[i] = v ? dst[e] : -1;
    fs[i] = v ? src[e] : 0;
  }
#pragma unroll
  for (int i = 0; i < 2; ++i)
    fp[i] = (fd[i] >= 0) ? atomicAdd(&cursor[fd[i]], 1) : BCAP;
#pragma unroll
  for (int i = 0; i < 2; ++i)
    if (fp[i] < BCAP) colbuk[(size_t)fd[i] * BCAP + fp[i]] = fs[i];
}

// ---------------- prep: dinv, z = Wo.h0, v0 = dinv*z --------------------------
// Propagation commutes with the feature->scalar projection (A acts on nodes,
// Wo on features; ReLU is encoder-only), so ALL 10 APPNP steps run on scalars.
__global__ __launch_bounds__(256, 8) void prep(
    const unsigned* __restrict__ h0b, const int* __restrict__ deg,
    const float* __restrict__ Wo, float* __restrict__ dinv,
    float* __restrict__ z, float* __restrict__ v0)
{
  int node = blockIdx.x * 4 + (threadIdx.x >> 6);
  if (node >= NN) return;
  int lane = threadIdx.x & 63;
  unsigned w = h0b[(size_t)node * 64 + lane];
  float2 wv = ((const float2*)Wo)[lane];
  float p = bflo(w) * wv.x + bfhi(w) * wv.y;
#pragma unroll
  for (int off = 32; off > 0; off >>= 1) p += __shfl_down(p, off, 64);
  if (lane == 0) {
    float di = rsqrtf((float)(deg[node] + 1));   // +1 self-loop
    dinv[node] = di;
    z[node] = p;
    v0[node] = di * p;
  }
}

// ---------------- scalar APPNP step ------------------------------------------
// s' = 0.9*dinv*(sum_nbr v + v_self) + 0.1*z ; v' = dinv*s'. v = 400KB, L2-hot.
// 16 lanes/node (avg deg ~16, max ~40 -> <=3 gather iters), width-16 reduce.
template<int LAST>
__global__ __launch_bounds__(256, 8) void appnp_sstep(
    const float* __restrict__ vin, const float* __restrict__ z,
    const float* __restrict__ dinv, const int* __restrict__ deg,
    const int* __restrict__ colbuk, float* __restrict__ vout,
    const float* __restrict__ bo, float* __restrict__ out)
{
  int tid = threadIdx.x;
  int sl = tid & 15;
  int node = blockIdx.x * 16 + (tid >> 4);
  if (node >= NN) return;
  int m = min(deg[node], BCAP);
  float val = (sl == 0) ? vin[node] : 0.f;        // self-loop term
  for (int j = sl; j < m; j += 16)
    val += vin[colbuk[(size_t)node * BCAP + j]];
#pragma unroll
  for (int off = 8; off > 0; off >>= 1) val += __shfl_down(val, off, 16);
  if (sl == 0) {
    float di = dinv[node];
    float s = 0.9f * di * val + 0.1f * z[node];
    if (LAST) out[node] = s + bo[0];
    else vout[node] = di * s;
  }
}

// ---------------- launch -----------------------------------------------------
extern "C" void kernel_launch(void* const* d_in, const int* in_sizes, int n_in,
                              void* d_out, int out_size, void* d_ws, size_t ws_size,
                              hipStream_t stream) {
  const float* x   = (const float*)d_in[0];
  const int*   ei  = (const int*)d_in[1];     // [2, NE] flat: src then dst
  const float* W1  = (const float*)d_in[2];
  const float* b1  = (const float*)d_in[3];
  const float* W2  = (const float*)d_in[4];
  const float* b2  = (const float*)d_in[5];
  const float* W3  = (const float*)d_in[6];
  const float* b3  = (const float*)d_in[7];
  const float* Wo  = (const float*)d_in[8];
  const float* bo  = (const float*)d_in[9];
  float* out = (float*)d_out;

  const int* srcv = ei;
  const int* dstv = ei + NE;

  // workspace layout
  int*      colbuk = (int*)d_ws;                              // NN*BCAP
  unsigned* hb1    = (unsigned*)(colbuk + (size_t)NN * BCAP); // NN*64 (h1)
  unsigned* hb2    = hb1 + (size_t)NN * 64;                   // NN*64 (h2)
  unsigned* h0b    = hb2 + (size_t)NN * 64;                   // NN*64 (h0)
  float*    dinv   = (float*)(h0b + (size_t)NN * 64);         // NN
  int*      cursor = (int*)(dinv + NN);                       // NN (degree)
  float*    zbuf   = (float*)(cursor + NN);                   // NN
  float*    va     = zbuf + NN;                               // NN
  float*    vb     = va + NN;                                 // NN

  hipMemsetAsync(cursor, 0, (size_t)NN * 4, stream);

  // encoder GEMMs, each carrying a RIGHT-SIZED fill slice (200,704 edges =
  // 98 ILP-8 blocks; fill_time ~ gemm_time so launches end at gemm speed).
  const int ng = (NN + 127) / 128;            // 782 gemm blocks; grid 98*9=882
  fused_gemm_fill<1><<<882, 256, 0, stream>>>(
      x, W1, b1, (unsigned short*)hb1, NN, IND, ng,
      srcv, dstv, 0, 200704, cursor, colbuk);
  fused_gemm_fill<0><<<882, 256, 0, stream>>>(
      hb1, W2, b2, (unsigned short*)hb2, NN, HIDD, ng,
      srcv, dstv, 200704, 401408, cursor, colbuk);
  fused_gemm_fill<0><<<882, 256, 0, stream>>>(
      hb2, W3, b3, (unsigned short*)h0b, NN, HIDD, ng,
      srcv, dstv, 401408, FTAIL, cursor, colbuk);

  // remaining 997,888 edges at the full standalone rate (no LDS cap)
  bucket_fill_tail<<<1950, 256, 0, stream>>>(srcv, dstv, cursor, colbuk);

  // project to scalars: z = Wo.h0, v0 = dinv*z (fill complete; cursor==degree)
  prep<<<(NN + 3) / 4, 256, 0, stream>>>(h0b, cursor, Wo, dinv, zbuf, va);

  // 10 scalar propagation steps (pure fp32 — no quantization in propagation)
  int ssb = (NN + 15) / 16;
  float* cur = va; float* nxt = vb;
  for (int k = 0; k < 9; ++k) {
    appnp_sstep<0><<<ssb, 256, 0, stream>>>(cur, zbuf, dinv, cursor, colbuk,
                                            nxt, nullptr, nullptr);
    float* t = cur; cur = nxt; nxt = t;
  }
  appnp_sstep<1><<<ssb, 256, 0, stream>>>(cur, zbuf, dinv, cursor, colbuk,
                                          nullptr, bo, out);
}

// Round 19
// 257.954 us; speedup vs baseline: 1.1235x; 1.1235x over previous
//
#include <hip/hip_runtime.h>

#define NN   100000
#define NE   1600000
#define IND  256
#define HIDD 128
#define BCAP 64      // per-node bucket capacity (max in-degree ~40 for this input)
#define NPART 196    // dst>>9 windows of 512 nodes (196*512 = 100352 >= NN)
#define SCAP 10240   // stream capacity: mean 8192 + 22 sigma

typedef __attribute__((ext_vector_type(8))) short short8v;
typedef __attribute__((ext_vector_type(4))) float f32x4;

// ---------------- bf16 helpers ----------------------------------------------
__device__ inline float bflo(unsigned w) { return __uint_as_float(w << 16); }
__device__ inline float bfhi(unsigned w) { return __uint_as_float(w & 0xffff0000u); }
__device__ inline unsigned packbf2(float x, float y) {   // RNE round both
  unsigned xb = __float_as_uint(x);
  unsigned yb = __float_as_uint(y);
  xb += 0x7fffu + ((xb >> 16) & 1u);
  yb += 0x7fffu + ((yb >> 16) & 1u);
  return (xb >> 16) | (yb & 0xffff0000u);
}
__device__ inline unsigned short bf16r(float x) {        // RNE round one
  unsigned b = __float_as_uint(x);
  b += 0x7fffu + ((b >> 16) & 1u);
  return (unsigned short)(b >> 16);
}

// ---------------- fill phase A: radix partition into 196 streams --------------
// Replaces the direct atomic+scatter fill (r6-r18: pinned at ~12.6 Gedge/s by
// 1.6M global cursor RMWs + 1.6M random 4B stores, all on cross-XCD-shared
// lines). Here: per-block LDS histogram -> 196 span reservations (153K global
// atomics TOTAL) -> dense block-private span writes (write-combined). Entry =
// (dst&511)<<17 | src (26 bits).
__global__ __launch_bounds__(256, 8) void fill_phaseA(
    const int* __restrict__ src, const int* __restrict__ dst,
    int* __restrict__ gcur, unsigned* __restrict__ sbuf)
{
  __shared__ int hist[NPART];
  __shared__ int lofs[NPART];
  const int tid = threadIdx.x;
  const int base = blockIdx.x * 2048;
  for (int i = tid; i < NPART; i += 256) hist[i] = 0;
  __syncthreads();
  int d[8], s[8];
#pragma unroll
  for (int i = 0; i < 8; ++i) {
    int e = base + i * 256 + tid;
    bool v = e < NE;
    d[i] = v ? dst[e] : -1;
    s[i] = v ? src[e] : 0;
    if (v) atomicAdd(&hist[d[i] >> 9], 1);
  }
  __syncthreads();
  for (int i = tid; i < NPART; i += 256)
    lofs[i] = atomicAdd(&gcur[i], hist[i]);     // global span reservation
  __syncthreads();
#pragma unroll
  for (int i = 0; i < 8; ++i) {
    if (d[i] >= 0) {
      int p = d[i] >> 9;
      int q = atomicAdd(&lofs[p], 1);           // LDS: offset within stream
      if (q < SCAP)
        sbuf[(size_t)p * SCAP + q] = ((unsigned)(d[i] & 511) << 17) | (unsigned)s[i];
    }
  }
}

// ---------------- fill phase B: per-window scatter with LDS cursors -----------
// One block per 512-node window: cursors in LDS (ZERO global atomics), colbuk
// writes land in a 128KB window owned by THIS block only -> every 64B line is
// single-writer, accumulates in one L2, flushes once. deg written coalesced.
__global__ __launch_bounds__(256, 8) void fill_phaseB(
    const unsigned* __restrict__ sbuf, const int* __restrict__ gcur,
    int* __restrict__ colbuk, int* __restrict__ deg)
{
  __shared__ int lcur[512];
  const int tid = threadIdx.x;
  const int b = blockIdx.x;
  for (int i = tid; i < 512; i += 256) lcur[i] = 0;
  __syncthreads();
  int cnt = min(gcur[b], SCAP);
  const unsigned* sp = sbuf + (size_t)b * SCAP;
  for (int i = tid; i < cnt; i += 256) {
    unsigned u = sp[i];
    int dloc = (int)(u >> 17);
    int s = (int)(u & 0x1FFFFu);
    int pos = atomicAdd(&lcur[dloc], 1);
    if (pos < BCAP) colbuk[(size_t)((b << 9) + dloc) * BCAP + pos] = s;
  }
  __syncthreads();
  for (int i = tid; i < 512; i += 256) {
    int node = (b << 9) + i;
    if (node < NN) deg[node] = lcur[i];         // true in-degree (uncapped)
  }
}

// ---------------- pure MFMA GEMM: C = relu(A @ B^T + bias) --------------------
// 128x128 tile, 4 waves, BK=32 (LDS 20.5KB). B = fp32 weights, bf16 in staging.
// NOTE (r15): grid.sync() ~140us/barrier on 8-XCD MI355X — never again.
#define APITCH 40   // padded row pitch in bf16 elems (32 + 8): 80 B, 16B-aligned
template<int A_FP32>
__global__ __launch_bounds__(256) void gemm_bias_relu(
    const void* __restrict__ Aptr, const float* __restrict__ Bf,
    const float* __restrict__ bias, unsigned short* __restrict__ Cb,
    int M, int K)
{
  __shared__ unsigned short lA[128 * APITCH];
  __shared__ unsigned short lB[128 * APITCH];
  const int tid = threadIdx.x;
  const int lane = tid & 63, wid = tid >> 6;
  const int wr = wid >> 1, wc = wid & 1;
  const int bm = blockIdx.x * 128;
  const int lr = lane & 15, lg = lane >> 4;

  f32x4 acc[4][4];
#pragma unroll
  for (int i = 0; i < 4; ++i)
#pragma unroll
    for (int j = 0; j < 4; ++j) acc[i][j] = (f32x4){0.f, 0.f, 0.f, 0.f};

  for (int k0 = 0; k0 < K; k0 += 32) {
#pragma unroll
    for (int s0 = 0; s0 < 512; s0 += 256) {
      int s = s0 + tid;
      int rr = s >> 2, g = s & 3;
      int grow = bm + rr;
      if (A_FP32) {
        float4 v0 = make_float4(0.f, 0.f, 0.f, 0.f);
        float4 v1 = v0;
        if (grow < M) {
          const float* ap = (const float*)Aptr + (size_t)grow * K + k0 + g * 8;
          v0 = ((const float4*)ap)[0];
          v1 = ((const float4*)ap)[1];
        }
        uint4 pk;
        pk.x = packbf2(v0.x, v0.y); pk.y = packbf2(v0.z, v0.w);
        pk.z = packbf2(v1.x, v1.y); pk.w = packbf2(v1.z, v1.w);
        *(uint4*)&lA[rr * APITCH + g * 8] = pk;
      } else {
        uint4 v = make_uint4(0u, 0u, 0u, 0u);
        if (grow < M)
          v = *(const uint4*)((const unsigned short*)Aptr + (size_t)grow * K + k0 + g * 8);
        *(uint4*)&lA[rr * APITCH + g * 8] = v;
      }
      {  // B: fp32 weights -> bf16 in staging
        const float* bp = Bf + (size_t)rr * K + k0 + g * 8;
        float4 w0 = ((const float4*)bp)[0];
        float4 w1 = ((const float4*)bp)[1];
        uint4 pk;
        pk.x = packbf2(w0.x, w0.y); pk.y = packbf2(w0.z, w0.w);
        pk.z = packbf2(w1.x, w1.y); pk.w = packbf2(w1.z, w1.w);
        *(uint4*)&lB[rr * APITCH + g * 8] = pk;
      }
    }
    __syncthreads();
    {
      short8v a[4], b[4];
#pragma unroll
      for (int i = 0; i < 4; ++i)
        a[i] = *(const short8v*)&lA[(wr * 64 + i * 16 + lr) * APITCH + lg * 8];
#pragma unroll
      for (int j = 0; j < 4; ++j)
        b[j] = *(const short8v*)&lB[(wc * 64 + j * 16 + lr) * APITCH + lg * 8];
#pragma unroll
      for (int i = 0; i < 4; ++i)
#pragma unroll
        for (int j = 0; j < 4; ++j)
          acc[i][j] = __builtin_amdgcn_mfma_f32_16x16x32_bf16(a[i], b[j], acc[i][j], 0, 0, 0);
    }
    __syncthreads();
  }

  // epilogue: C/D layout col=lane&15, row=(lane>>4)*4+e  (m89-verified)
#pragma unroll
  for (int i = 0; i < 4; ++i)
#pragma unroll
    for (int e = 0; e < 4; ++e) {
      int row = bm + wr * 64 + i * 16 + lg * 4 + e;
      if (row < M) {
#pragma unroll
        for (int j = 0; j < 4; ++j) {
          int cc = wc * 64 + j * 16 + lr;
          float t = fmaxf(acc[i][j][e] + bias[cc], 0.f);
          Cb[(size_t)row * 128 + cc] = bf16r(t);
        }
      }
    }
}

// ---------------- prep: dinv, z = Wo.h0, v0 = dinv*z --------------------------
// Propagation commutes with the feature->scalar projection (A acts on nodes,
// Wo on features; ReLU is encoder-only), so ALL 10 APPNP steps run on scalars.
__global__ __launch_bounds__(256, 8) void prep(
    const unsigned* __restrict__ h0b, const int* __restrict__ deg,
    const float* __restrict__ Wo, float* __restrict__ dinv,
    float* __restrict__ z, float* __restrict__ v0)
{
  int node = blockIdx.x * 4 + (threadIdx.x >> 6);
  if (node >= NN) return;
  int lane = threadIdx.x & 63;
  unsigned w = h0b[(size_t)node * 64 + lane];
  float2 wv = ((const float2*)Wo)[lane];
  float p = bflo(w) * wv.x + bfhi(w) * wv.y;
#pragma unroll
  for (int off = 32; off > 0; off >>= 1) p += __shfl_down(p, off, 64);
  if (lane == 0) {
    float di = rsqrtf((float)(deg[node] + 1));   // +1 self-loop
    dinv[node] = di;
    z[node] = p;
    v0[node] = di * p;
  }
}

// ---------------- scalar APPNP step ------------------------------------------
// s' = 0.9*dinv*(sum_nbr v + v_self) + 0.1*z ; v' = dinv*s'. v = 400KB, L2-hot.
// 16 lanes/node (avg deg ~16, max ~40 -> <=3 gather iters), width-16 reduce.
template<int LAST>
__global__ __launch_bounds__(256, 8) void appnp_sstep(
    const float* __restrict__ vin, const float* __restrict__ z,
    const float* __restrict__ dinv, const int* __restrict__ deg,
    const int* __restrict__ colbuk, float* __restrict__ vout,
    const float* __restrict__ bo, float* __restrict__ out)
{
  int tid = threadIdx.x;
  int sl = tid & 15;
  int node = blockIdx.x * 16 + (tid >> 4);
  if (node >= NN) return;
  int m = min(deg[node], BCAP);
  float val = (sl == 0) ? vin[node] : 0.f;        // self-loop term
  for (int j = sl; j < m; j += 16)
    val += vin[colbuk[(size_t)node * BCAP + j]];
#pragma unroll
  for (int off = 8; off > 0; off >>= 1) val += __shfl_down(val, off, 16);
  if (sl == 0) {
    float di = dinv[node];
    float s = 0.9f * di * val + 0.1f * z[node];
    if (LAST) out[node] = s + bo[0];
    else vout[node] = di * s;
  }
}

// ---------------- launch -----------------------------------------------------
extern "C" void kernel_launch(void* const* d_in, const int* in_sizes, int n_in,
                              void* d_out, int out_size, void* d_ws, size_t ws_size,
                              hipStream_t stream) {
  const float* x   = (const float*)d_in[0];
  const int*   ei  = (const int*)d_in[1];     // [2, NE] flat: src then dst
  const float* W1  = (const float*)d_in[2];
  const float* b1  = (const float*)d_in[3];
  const float* W2  = (const float*)d_in[4];
  const float* b2  = (const float*)d_in[5];
  const float* W3  = (const float*)d_in[6];
  const float* b3  = (const float*)d_in[7];
  const float* Wo  = (const float*)d_in[8];
  const float* bo  = (const float*)d_in[9];
  float* out = (float*)d_out;

  const int* srcv = ei;
  const int* dstv = ei + NE;

  // workspace layout
  int*      colbuk = (int*)d_ws;                              // NN*BCAP
  unsigned* sbuf   = (unsigned*)(colbuk + (size_t)NN * BCAP); // NPART*SCAP
  int*      gcur   = (int*)(sbuf + (size_t)NPART * SCAP);     // NPART
  int*      deg    = gcur + NPART;                            // NN
  unsigned* hb1    = (unsigned*)(deg + NN);                   // NN*64 (h1)
  unsigned* hb2    = hb1 + (size_t)NN * 64;                   // NN*64 (h2)
  unsigned* h0b    = hb2 + (size_t)NN * 64;                   // NN*64 (h0)
  float*    dinv   = (float*)(h0b + (size_t)NN * 64);         // NN
  float*    zbuf   = dinv + NN;                               // NN
  float*    va     = zbuf + NN;                               // NN
  float*    vb     = va + NN;                                 // NN

  hipMemsetAsync(gcur, 0, NPART * 4, stream);

  // graph build: radix partition (A) + LDS-cursor scatter (B)
  fill_phaseA<<<(NE + 2047) / 2048, 256, 0, stream>>>(srcv, dstv, gcur, sbuf);
  fill_phaseB<<<NPART, 256, 0, stream>>>(sbuf, gcur, colbuk, deg);

  // encoder GEMMs (pure)
  const int ng = (NN + 127) / 128;            // 782 blocks
  gemm_bias_relu<1><<<ng, 256, 0, stream>>>(x,   W1, b1, (unsigned short*)hb1, NN, IND);
  gemm_bias_relu<0><<<ng, 256, 0, stream>>>(hb1, W2, b2, (unsigned short*)hb2, NN, HIDD);
  gemm_bias_relu<0><<<ng, 256, 0, stream>>>(hb2, W3, b3, (unsigned short*)h0b, NN, HIDD);

  // project to scalars: z = Wo.h0, v0 = dinv*z
  prep<<<(NN + 3) / 4, 256, 0, stream>>>(h0b, deg, Wo, dinv, zbuf, va);

  // 10 scalar propagation steps (pure fp32 — no quantization in propagation)
  int ssb = (NN + 15) / 16;
  float* cur = va; float* nxt = vb;
  for (int k = 0; k < 9; ++k) {
    appnp_sstep<0><<<ssb, 256, 0, stream>>>(cur, zbuf, dinv, deg, colbuk,
                                            nxt, nullptr, nullptr);
    float* t = cur; cur = nxt; nxt = t;
  }
  appnp_sstep<1><<<ssb, 256, 0, stream>>>(cur, zbuf, dinv, deg, colbuk,
                                          nullptr, bo, out);
}

// Round 20
// 216.337 us; speedup vs baseline: 1.3397x; 1.1924x over previous
//
#include <hip/hip_runtime.h>

#define NN   100000
#define NE   1600000
#define IND  256
#define HIDD 128
#define BCAP 64      // per-node bucket capacity (max in-degree ~40 for this input)
#define NPART 196    // dst>>9 windows of 512 nodes (196*512 = 100352 >= NN)
#define SCAP 10240   // stream capacity: mean 8163 + 23 sigma
#define APITCH 40    // staging row pitch in bf16 elems (32+8): 80 B, 16B-aligned
#define HPITCH 136   // h-tile row pitch (128+8): 272 B, 16B-aligned

typedef __attribute__((ext_vector_type(8))) short short8v;
typedef __attribute__((ext_vector_type(4))) float f32x4;

// ---------------- bf16 helpers ----------------------------------------------
__device__ inline float bflo(unsigned w) { return __uint_as_float(w << 16); }
__device__ inline float bfhi(unsigned w) { return __uint_as_float(w & 0xffff0000u); }
__device__ inline unsigned packbf2(float x, float y) {   // RNE round both
  unsigned xb = __float_as_uint(x);
  unsigned yb = __float_as_uint(y);
  xb += 0x7fffu + ((xb >> 16) & 1u);
  yb += 0x7fffu + ((yb >> 16) & 1u);
  return (xb >> 16) | (yb & 0xffff0000u);
}
__device__ inline unsigned short bf16r(float x) {        // RNE round one
  unsigned b = __float_as_uint(x);
  b += 0x7fffu + ((b >> 16) & 1u);
  return (unsigned short)(b >> 16);
}

// ---------------- fill phase A: radix partition into 196 streams --------------
// Per-block LDS histogram -> 196 span reservations (153K global atomics TOTAL,
// not 1.6M) -> dense block-private span writes (write-combined). Entry =
// (dst&511)<<17 | src (26 bits). Replaces direct atomic+scatter (r6-r18 wall).
__global__ __launch_bounds__(256, 8) void fill_phaseA(
    const int* __restrict__ src, const int* __restrict__ dst,
    int* __restrict__ gcur, unsigned* __restrict__ sbuf)
{
  __shared__ int hist[NPART];
  __shared__ int lofs[NPART];
  const int tid = threadIdx.x;
  const int base = blockIdx.x * 2048;
  for (int i = tid; i < NPART; i += 256) hist[i] = 0;
  __syncthreads();
  int d[8], s[8];
#pragma unroll
  for (int i = 0; i < 8; ++i) {
    int e = base + i * 256 + tid;
    bool v = e < NE;
    d[i] = v ? dst[e] : -1;
    s[i] = v ? src[e] : 0;
    if (v) atomicAdd(&hist[d[i] >> 9], 1);
  }
  __syncthreads();
  for (int i = tid; i < NPART; i += 256)
    lofs[i] = atomicAdd(&gcur[i], hist[i]);     // global span reservation
  __syncthreads();
#pragma unroll
  for (int i = 0; i < 8; ++i) {
    if (d[i] >= 0) {
      int p = d[i] >> 9;
      int q = atomicAdd(&lofs[p], 1);           // LDS: offset within stream
      if (q < SCAP)
        sbuf[(size_t)p * SCAP + q] = ((unsigned)(d[i] & 511) << 17) | (unsigned)s[i];
    }
  }
}

// ---------------- fill phase B: per-window scatter with LDS cursors -----------
// One block per 512-node window: cursors in LDS (ZERO global atomics), colbuk
// writes land in a 128KB window owned by THIS block only -> single-writer
// lines, flush once. deg written coalesced.
__global__ __launch_bounds__(256, 8) void fill_phaseB(
    const unsigned* __restrict__ sbuf, const int* __restrict__ gcur,
    int* __restrict__ colbuk, int* __restrict__ deg)
{
  __shared__ int lcur[512];
  const int tid = threadIdx.x;
  const int b = blockIdx.x;
  for (int i = tid; i < 512; i += 256) lcur[i] = 0;
  __syncthreads();
  int cnt = min(gcur[b], SCAP);
  const unsigned* sp = sbuf + (size_t)b * SCAP;
  for (int i = tid; i < cnt; i += 256) {
    unsigned u = sp[i];
    int dloc = (int)(u >> 17);
    int s = (int)(u & 0x1FFFFu);
    int pos = atomicAdd(&lcur[dloc], 1);
    if (pos < BCAP) colbuk[(size_t)((b << 9) + dloc) * BCAP + pos] = s;
  }
  __syncthreads();
  for (int i = tid; i < 512; i += 256) {
    int node = (b << 9) + i;
    if (node < NN) deg[node] = lcur[i];         // true in-degree (uncapped)
  }
}

// ---------------- fully fused encoder: x -> h1 -> h2 -> h0 -> z ---------------
// The scalar-propagation algebra needs ONLY z = Wo.h0 (400 KB) from the
// encoder, so h1/h2/h0 never touch HBM: each block chains 3 MFMA phases with
// the running h-tile in LDS (hbuf [128][136] bf16). Phase 1 staging buffer lA
// ALIASES hbuf (h1 written only after the K-loop's last barrier). Weights
// streamed fp32->bf16 per 32-col chunk (L2-hot after first blocks). Global
// traffic: x 102 MB (full 128B lines, fp32 BK=32) + z 400 KB — vs r19's 3
// separate gemms at 67-70 us each, 2x-fetched A and 25 MB C per layer.
// z epilogue = r13's verified ZOUT reduce. LDS 46 KB -> 3 blocks/CU.
// NOTE (r15): grid.sync() ~140us/barrier on 8-XCD MI355X — never again.
__global__ __launch_bounds__(256) void enc_fused(
    const float* __restrict__ x,
    const float* __restrict__ W1, const float* __restrict__ b1,
    const float* __restrict__ W2, const float* __restrict__ b2,
    const float* __restrict__ W3, const float* __restrict__ b3,
    const float* __restrict__ Wo, float* __restrict__ z)
{
  __shared__ unsigned short hbuf[128 * HPITCH];   // h-tile; aliases lA in ph.1
  __shared__ unsigned short lB[128 * APITCH];     // B staging
  __shared__ float zsh[2][128];
  unsigned short* lA = hbuf;
  const int tid = threadIdx.x;
  const int lane = tid & 63, wid = tid >> 6;
  const int wr = wid >> 1, wc = wid & 1;
  const int bm = blockIdx.x * 128;
  const int lr = lane & 15, lg = lane >> 4;

  f32x4 acc[4][4];
#pragma unroll
  for (int i = 0; i < 4; ++i)
#pragma unroll
    for (int j = 0; j < 4; ++j) acc[i][j] = (f32x4){0.f, 0.f, 0.f, 0.f};

  // ---- phase 1: h1 = relu(x @ W1^T + b1), x fp32 K=256 ----
  for (int k0 = 0; k0 < IND; k0 += 32) {
#pragma unroll
    for (int s0 = 0; s0 < 512; s0 += 256) {
      int s = s0 + tid, rr = s >> 2, g = s & 3;
      int grow = bm + rr;
      float4 v0 = make_float4(0.f, 0.f, 0.f, 0.f), v1 = v0;
      if (grow < NN) {
        const float* ap = x + (size_t)grow * IND + k0 + g * 8;
        v0 = ((const float4*)ap)[0]; v1 = ((const float4*)ap)[1];
      }
      uint4 pk;
      pk.x = packbf2(v0.x, v0.y); pk.y = packbf2(v0.z, v0.w);
      pk.z = packbf2(v1.x, v1.y); pk.w = packbf2(v1.z, v1.w);
      *(uint4*)&lA[rr * APITCH + g * 8] = pk;
      const float* bp = W1 + (size_t)rr * IND + k0 + g * 8;
      float4 w0 = ((const float4*)bp)[0], w1 = ((const float4*)bp)[1];
      uint4 pb;
      pb.x = packbf2(w0.x, w0.y); pb.y = packbf2(w0.z, w0.w);
      pb.z = packbf2(w1.x, w1.y); pb.w = packbf2(w1.z, w1.w);
      *(uint4*)&lB[rr * APITCH + g * 8] = pb;
    }
    __syncthreads();
    {
      short8v a[4], b[4];
#pragma unroll
      for (int i = 0; i < 4; ++i)
        a[i] = *(const short8v*)&lA[(wr * 64 + i * 16 + lr) * APITCH + lg * 8];
#pragma unroll
      for (int j = 0; j < 4; ++j)
        b[j] = *(const short8v*)&lB[(wc * 64 + j * 16 + lr) * APITCH + lg * 8];
#pragma unroll
      for (int i = 0; i < 4; ++i)
#pragma unroll
        for (int j = 0; j < 4; ++j)
          acc[i][j] = __builtin_amdgcn_mfma_f32_16x16x32_bf16(a[i], b[j], acc[i][j], 0, 0, 0);
    }
    __syncthreads();
  }
  // write h1 -> hbuf (staging data dead; all reads drained by last barrier)
#pragma unroll
  for (int i = 0; i < 4; ++i)
#pragma unroll
    for (int e = 0; e < 4; ++e) {
      int lrow = wr * 64 + i * 16 + lg * 4 + e;
#pragma unroll
      for (int j = 0; j < 4; ++j) {
        int cc = wc * 64 + j * 16 + lr;
        hbuf[lrow * HPITCH + cc] = bf16r(fmaxf(acc[i][j][e] + b1[cc], 0.f));
      }
    }
  __syncthreads();

  // ---- phase 2: h2 = relu(h1 @ W2^T + b2), A from hbuf ----
#pragma unroll
  for (int i = 0; i < 4; ++i)
#pragma unroll
    for (int j = 0; j < 4; ++j) acc[i][j] = (f32x4){0.f, 0.f, 0.f, 0.f};
  for (int k0 = 0; k0 < HIDD; k0 += 32) {
#pragma unroll
    for (int s0 = 0; s0 < 512; s0 += 256) {
      int s = s0 + tid, rr = s >> 2, g = s & 3;
      const float* bp = W2 + (size_t)rr * HIDD + k0 + g * 8;
      float4 w0 = ((const float4*)bp)[0], w1 = ((const float4*)bp)[1];
      uint4 pb;
      pb.x = packbf2(w0.x, w0.y); pb.y = packbf2(w0.z, w0.w);
      pb.z = packbf2(w1.x, w1.y); pb.w = packbf2(w1.z, w1.w);
      *(uint4*)&lB[rr * APITCH + g * 8] = pb;
    }
    __syncthreads();
    {
      short8v a[4], b[4];
#pragma unroll
      for (int i = 0; i < 4; ++i)
        a[i] = *(const short8v*)&hbuf[(wr * 64 + i * 16 + lr) * HPITCH + k0 + lg * 8];
#pragma unroll
      for (int j = 0; j < 4; ++j)
        b[j] = *(const short8v*)&lB[(wc * 64 + j * 16 + lr) * APITCH + lg * 8];
#pragma unroll
      for (int i = 0; i < 4; ++i)
#pragma unroll
        for (int j = 0; j < 4; ++j)
          acc[i][j] = __builtin_amdgcn_mfma_f32_16x16x32_bf16(a[i], b[j], acc[i][j], 0, 0, 0);
    }
    __syncthreads();
  }
  // write h2 -> hbuf (h1 fully consumed)
#pragma unroll
  for (int i = 0; i < 4; ++i)
#pragma unroll
    for (int e = 0; e < 4; ++e) {
      int lrow = wr * 64 + i * 16 + lg * 4 + e;
#pragma unroll
      for (int j = 0; j < 4; ++j) {
        int cc = wc * 64 + j * 16 + lr;
        hbuf[lrow * HPITCH + cc] = bf16r(fmaxf(acc[i][j][e] + b2[cc], 0.f));
      }
    }
  __syncthreads();

  // ---- phase 3: h0 = relu(h2 @ W3^T + b3) -> z = Wo . h0 (never stored) ----
#pragma unroll
  for (int i = 0; i < 4; ++i)
#pragma unroll
    for (int j = 0; j < 4; ++j) acc[i][j] = (f32x4){0.f, 0.f, 0.f, 0.f};
  for (int k0 = 0; k0 < HIDD; k0 += 32) {
#pragma unroll
    for (int s0 = 0; s0 < 512; s0 += 256) {
      int s = s0 + tid, rr = s >> 2, g = s & 3;
      const float* bp = W3 + (size_t)rr * HIDD + k0 + g * 8;
      float4 w0 = ((const float4*)bp)[0], w1 = ((const float4*)bp)[1];
      uint4 pb;
      pb.x = packbf2(w0.x, w0.y); pb.y = packbf2(w0.z, w0.w);
      pb.z = packbf2(w1.x, w1.y); pb.w = packbf2(w1.z, w1.w);
      *(uint4*)&lB[rr * APITCH + g * 8] = pb;
    }
    __syncthreads();
    {
      short8v a[4], b[4];
#pragma unroll
      for (int i = 0; i < 4; ++i)
        a[i] = *(const short8v*)&hbuf[(wr * 64 + i * 16 + lr) * HPITCH + k0 + lg * 8];
#pragma unroll
      for (int j = 0; j < 4; ++j)
        b[j] = *(const short8v*)&lB[(wc * 64 + j * 16 + lr) * APITCH + lg * 8];
#pragma unroll
      for (int i = 0; i < 4; ++i)
#pragma unroll
        for (int j = 0; j < 4; ++j)
          acc[i][j] = __builtin_amdgcn_mfma_f32_16x16x32_bf16(a[i], b[j], acc[i][j], 0, 0, 0);
    }
    __syncthreads();
  }
  // z epilogue (r13-verified): z[row] = sum_cc Wo[cc]*relu(acc+b3[cc])
  float wv[4];
#pragma unroll
  for (int j = 0; j < 4; ++j) wv[j] = Wo[wc * 64 + j * 16 + lr];
  zsh[tid >> 7][tid & 127] = 0.f;
  __syncthreads();
#pragma unroll
  for (int i = 0; i < 4; ++i)
#pragma unroll
    for (int e = 0; e < 4; ++e) {
      float part = 0.f;
#pragma unroll
      for (int j = 0; j < 4; ++j) {
        int cc = wc * 64 + j * 16 + lr;
        part += fmaxf(acc[i][j][e] + b3[cc], 0.f) * wv[j];
      }
#pragma unroll
      for (int off = 8; off > 0; off >>= 1) part += __shfl_down(part, off, 16);
      if (lr == 0) zsh[wc][wr * 64 + i * 16 + lg * 4 + e] = part;
    }
  __syncthreads();
  if (tid < 128) {
    int row = bm + tid;
    if (row < NN) z[row] = zsh[0][tid] + zsh[1][tid];
  }
}

// ---------------- prep: dinv + v0 = dinv*z (scalars only) ---------------------
__global__ void prep_scalar(const int* __restrict__ deg, const float* __restrict__ z,
                            float* __restrict__ dinv, float* __restrict__ va) {
  int i = blockIdx.x * 256 + threadIdx.x;
  if (i < NN) {
    float di = rsqrtf((float)(deg[i] + 1));   // +1 self-loop
    dinv[i] = di;
    va[i] = di * z[i];
  }
}

// ---------------- scalar APPNP step ------------------------------------------
// Propagation commutes with the Wo projection (A acts on nodes, Wo on
// features; ReLU is encoder-only) -> all 10 steps run on per-node scalars.
// s' = 0.9*dinv*(sum_nbr v + v_self) + 0.1*z ; v' = dinv*s'. v = 400KB L2-hot.
// 16 lanes/node (avg deg ~16, max ~40 -> <=3 gather iters), width-16 reduce.
template<int LAST>
__global__ __launch_bounds__(256, 8) void appnp_sstep(
    const float* __restrict__ vin, const float* __restrict__ z,
    const float* __restrict__ dinv, const int* __restrict__ deg,
    const int* __restrict__ colbuk, float* __restrict__ vout,
    const float* __restrict__ bo, float* __restrict__ out)
{
  int tid = threadIdx.x;
  int sl = tid & 15;
  int node = blockIdx.x * 16 + (tid >> 4);
  if (node >= NN) return;
  int m = min(deg[node], BCAP);
  float val = (sl == 0) ? vin[node] : 0.f;        // self-loop term
  for (int j = sl; j < m; j += 16)
    val += vin[colbuk[(size_t)node * BCAP + j]];
#pragma unroll
  for (int off = 8; off > 0; off >>= 1) val += __shfl_down(val, off, 16);
  if (sl == 0) {
    float di = dinv[node];
    float s = 0.9f * di * val + 0.1f * z[node];
    if (LAST) out[node] = s + bo[0];
    else vout[node] = di * s;
  }
}

// ---------------- launch -----------------------------------------------------
extern "C" void kernel_launch(void* const* d_in, const int* in_sizes, int n_in,
                              void* d_out, int out_size, void* d_ws, size_t ws_size,
                              hipStream_t stream) {
  const float* x   = (const float*)d_in[0];
  const int*   ei  = (const int*)d_in[1];     // [2, NE] flat: src then dst
  const float* W1  = (const float*)d_in[2];
  const float* b1  = (const float*)d_in[3];
  const float* W2  = (const float*)d_in[4];
  const float* b2  = (const float*)d_in[5];
  const float* W3  = (const float*)d_in[6];
  const float* b3  = (const float*)d_in[7];
  const float* Wo  = (const float*)d_in[8];
  const float* bo  = (const float*)d_in[9];
  float* out = (float*)d_out;

  const int* srcv = ei;
  const int* dstv = ei + NE;

  // workspace layout (h buffers GONE — encoder emits only z)
  int*      colbuk = (int*)d_ws;                              // NN*BCAP
  unsigned* sbuf   = (unsigned*)(colbuk + (size_t)NN * BCAP); // NPART*SCAP
  int*      gcur   = (int*)(sbuf + (size_t)NPART * SCAP);     // NPART
  int*      deg    = gcur + NPART;                            // NN
  float*    dinv   = (float*)(deg + NN);                      // NN
  float*    zbuf   = dinv + NN;                               // NN
  float*    va     = zbuf + NN;                               // NN
  float*    vb     = va + NN;                                 // NN

  hipMemsetAsync(gcur, 0, NPART * 4, stream);

  // graph build: radix partition (A) + LDS-cursor scatter (B)
  fill_phaseA<<<(NE + 2047) / 2048, 256, 0, stream>>>(srcv, dstv, gcur, sbuf);
  fill_phaseB<<<NPART, 256, 0, stream>>>(sbuf, gcur, colbuk, deg);

  // fully fused encoder: x -> (h1 -> h2 -> h0 in LDS) -> z
  const int ng = (NN + 127) / 128;            // 782 blocks
  enc_fused<<<ng, 256, 0, stream>>>(x, W1, b1, W2, b2, W3, b3, Wo, zbuf);

  // dinv + v0
  prep_scalar<<<(NN + 255) / 256, 256, 0, stream>>>(deg, zbuf, dinv, va);

  // 10 scalar propagation steps (pure fp32)
  int ssb = (NN + 15) / 16;
  float* cur = va; float* nxt = vb;
  for (int k = 0; k < 9; ++k) {
    appnp_sstep<0><<<ssb, 256, 0, stream>>>(cur, zbuf, dinv, deg, colbuk,
                                            nxt, nullptr, nullptr);
    float* t = cur; cur = nxt; nxt = t;
  }
  appnp_sstep<1><<<ssb, 256, 0, stream>>>(cur, zbuf, dinv, deg, colbuk,
                                          nullptr, bo, out);
}